// Round 4
// baseline (2661.992 us; speedup 1.0000x reference)
//
#include <hip/hip_runtime.h>

// ---- dims (fixed by problem) ----
#define B    32
#define P    196
#define ENC  2048
#define DEC  512
#define ATT  512
#define E    256
#define V    30000
#define VP   30080   // V padded to multiple of 128
#define L    21
#define T    20      // L-1
#define KX   (E + ENC)   // 2304

typedef unsigned short u16;
typedef __bf16 bf16x8 __attribute__((ext_vector_type(8)));
typedef float  f32x4  __attribute__((ext_vector_type(4)));

__device__ __forceinline__ u16 f2bf(float f) {
    union { float f; unsigned int i; } v; v.f = f;
    unsigned int i = v.i;
    return (u16)((i + 0x7fffu + ((i >> 16) & 1u)) >> 16);
}
__device__ __forceinline__ float bf2f(u16 u) {
    union { unsigned int i; float f; } v; v.i = ((unsigned int)u) << 16; return v.f;
}
__device__ __forceinline__ float wave_sum(float v) {
    #pragma unroll
    for (int o = 32; o > 0; o >>= 1) v += __shfl_down(v, o, 64);
    return v;
}
__device__ __forceinline__ float sigf(float x) { return 1.0f / (1.0f + expf(-x)); }

// ---- shared 128x128-tile GEMM body: C = A[128,K] * B[128,K]^T, bf16 in, f32 acc
// LDS layout (per matrix, 8 KB): 8 blocks of 16 rows; block g holds
// (row r16, k-chunk c) at u16 offset g*512 + (c*16 + r16)*8.
// Stores AND fragment reads are both `base + lane*16B` (conflict-free).
template<int LDA, int LDB, int KSTEPS>
__device__ __forceinline__ void gemm128_body(const u16* __restrict__ A,
                                             const u16* __restrict__ Bm,
                                             u16* As, u16* Bs, f32x4 acc[4][4]) {
    const int tid = threadIdx.x, lane = tid & 63;
    const int w = tid >> 6, wm = w >> 1, wn = w & 1;
    const int c = lane >> 4, r16 = lane & 15;
    const int g0 = w, g1 = 4 + w;                 // two 16-row blocks per wave
    const u16* gA0 = A  + (size_t)(g0 * 16 + r16) * LDA + c * 8;
    const u16* gA1 = A  + (size_t)(g1 * 16 + r16) * LDA + c * 8;
    const u16* gB0 = Bm + (size_t)(g0 * 16 + r16) * LDB + c * 8;
    const u16* gB1 = Bm + (size_t)(g1 * 16 + r16) * LDB + c * 8;
    u16* sA0 = As + g0 * 512 + lane * 8;
    u16* sA1 = As + g1 * 512 + lane * 8;
    u16* sB0 = Bs + g0 * 512 + lane * 8;
    u16* sB1 = Bs + g1 * 512 + lane * 8;
    for (int ks = 0; ks < KSTEPS; ks++) {
        const int ko = ks * 32;
        bf16x8 a0 = *reinterpret_cast<const bf16x8*>(gA0 + ko);
        bf16x8 a1 = *reinterpret_cast<const bf16x8*>(gA1 + ko);
        bf16x8 b0 = *reinterpret_cast<const bf16x8*>(gB0 + ko);
        bf16x8 b1 = *reinterpret_cast<const bf16x8*>(gB1 + ko);
        __syncthreads();   // previous iteration's LDS reads complete
        *reinterpret_cast<bf16x8*>(sA0) = a0;
        *reinterpret_cast<bf16x8*>(sA1) = a1;
        *reinterpret_cast<bf16x8*>(sB0) = b0;
        *reinterpret_cast<bf16x8*>(sB1) = b1;
        __syncthreads();
        bf16x8 af[4], bfr[4];
        #pragma unroll
        for (int i = 0; i < 4; i++) {
            af[i]  = *reinterpret_cast<const bf16x8*>(As + (wm * 4 + i) * 512 + lane * 8);
            bfr[i] = *reinterpret_cast<const bf16x8*>(Bs + (wn * 4 + i) * 512 + lane * 8);
        }
        #pragma unroll
        for (int i = 0; i < 4; i++)
            #pragma unroll
            for (int j = 0; j < 4; j++)
                acc[i][j] = __builtin_amdgcn_mfma_f32_16x16x32_bf16(af[i], bfr[j], acc[i][j], 0, 0, 0);
    }
}

// ---- once: f32 -> bf16 conversion (4 elems/thread) ----
__global__ void k_f2b4(const float* __restrict__ s, u16* __restrict__ d, int n4) {
    int i = blockIdx.x * 256 + threadIdx.x;
    if (i < n4) {
        float4 v = reinterpret_cast<const float4*>(s)[i];
        ushort4 o;
        o.x = f2bf(v.x); o.y = f2bf(v.y); o.z = f2bf(v.z); o.w = f2bf(v.w);
        reinterpret_cast<ushort4*>(d)[i] = o;
    }
}
// zero-padded variant for Wfc (rows V..VP zeroed)
__global__ void k_f2bpad(const float* __restrict__ s, u16* __restrict__ d,
                         int n_src4, int n_dst4) {
    int i = blockIdx.x * 256 + threadIdx.x;
    if (i >= n_dst4) return;
    ushort4 o = {0, 0, 0, 0};
    if (i < n_src4) {
        float4 v = reinterpret_cast<const float4*>(s)[i];
        o.x = f2bf(v.x); o.y = f2bf(v.y); o.z = f2bf(v.z); o.w = f2bf(v.w);
    }
    reinterpret_cast<ushort4*>(d)[i] = o;
}

// ---- once: mean over P of encoder_out (f32) -> f32 [B,ENC] ----
__global__ void k_mean(const float* __restrict__ enc, float* __restrict__ mean) {
    int idx = blockIdx.x * 256 + threadIdx.x;
    int b = idx >> 11, e = idx & 2047;
    const float* p = enc + (size_t)b * P * ENC + e;
    float s = 0.f;
    for (int i = 0; i < P; i++) s += p[(size_t)i * ENC];
    mean[idx] = s * (1.0f / 196.0f);
}

// ---- once: h0/c0 = mean @ W^T + b ----
__global__ void k_h0c0(const float* __restrict__ mean,
                       const float* __restrict__ Wh0, const float* __restrict__ bh0,
                       const float* __restrict__ Wc0, const float* __restrict__ bc0,
                       u16* __restrict__ h, float* __restrict__ c) {
    int wid = (blockIdx.x * 256 + threadIdx.x) >> 6;
    int lane = threadIdx.x & 63;
    int b = wid >> 10, j = wid & 1023;
    bool is_h = j < DEC;
    int jj = is_h ? j : j - DEC;
    const float* W = is_h ? Wh0 : Wc0;
    const float* mrow = mean + b * ENC;
    const float* wrow = W + (size_t)jj * ENC;
    float acc = 0.f;
    #pragma unroll
    for (int kk = 0; kk < 4; kk++) {
        int k = kk * 512 + lane * 8;
        float4 a0 = *reinterpret_cast<const float4*>(mrow + k);
        float4 a1 = *reinterpret_cast<const float4*>(mrow + k + 4);
        float4 w0 = *reinterpret_cast<const float4*>(wrow + k);
        float4 w1 = *reinterpret_cast<const float4*>(wrow + k + 4);
        acc += a0.x * w0.x + a0.y * w0.y + a0.z * w0.z + a0.w * w0.w;
        acc += a1.x * w1.x + a1.y * w1.y + a1.z * w1.z + a1.w * w1.w;
    }
    acc = wave_sum(acc);
    if (lane == 0) {
        acc += is_h ? bh0[jj] : bc0[jj];
        if (is_h) h[b * DEC + jj] = f2bf(acc);
        else      c[b * DEC + jj] = acc;
    }
}

// ---- once: initial att2 from h0 (wave per output) ----
__global__ void k_att2w(const u16* __restrict__ h, const float* __restrict__ Wd,
                        const float* __restrict__ bd, float* __restrict__ att2) {
    int wid = (blockIdx.x * 256 + threadIdx.x) >> 6;
    int lane = threadIdx.x & 63;
    int b = wid >> 9, a = wid & 511;
    bf16x8 hv = *reinterpret_cast<const bf16x8*>(h + b * DEC + lane * 8);
    const float4* wd = reinterpret_cast<const float4*>(Wd + (size_t)a * DEC + lane * 8);
    float4 w0 = wd[0], w1 = wd[1];
    float acc = (float)hv[0] * w0.x + (float)hv[1] * w0.y + (float)hv[2] * w0.z + (float)hv[3] * w0.w
              + (float)hv[4] * w1.x + (float)hv[5] * w1.y + (float)hv[6] * w1.z + (float)hv[7] * w1.w;
    acc = wave_sum(acc);
    if (lane == 0) att2[b * ATT + a] = acc + bd[a];
}

// ---- once: att1 = enc @ We^T + be -> bf16 [B*P, ATT]  (tiled MFMA) ----
__global__ __launch_bounds__(256) void k_att1t(const u16* __restrict__ enc,
                                               const u16* __restrict__ We,
                                               const float* __restrict__ be,
                                               u16* __restrict__ att1) {
    __shared__ u16 As[128 * 32];
    __shared__ u16 Bs[128 * 32];
    f32x4 acc[4][4];
    const f32x4 z = {0.f, 0.f, 0.f, 0.f};
    #pragma unroll
    for (int i = 0; i < 4; i++)
        #pragma unroll
        for (int j = 0; j < 4; j++) acc[i][j] = z;
    const u16* A  = enc + (size_t)blockIdx.x * 128 * ENC;
    const u16* Bm = We  + (size_t)blockIdx.y * 128 * ENC;
    gemm128_body<ENC, ENC, 64>(A, Bm, As, Bs, acc);
    int tid = threadIdx.x, w = tid >> 6, lane = tid & 63;
    int wm = w >> 1, wn = w & 1, quad = lane >> 4, l16 = lane & 15;
    int mbase = blockIdx.x * 128 + wm * 64, nbase = blockIdx.y * 128 + wn * 64;
    #pragma unroll
    for (int i = 0; i < 4; i++)
        #pragma unroll
        for (int j = 0; j < 4; j++)
            #pragma unroll
            for (int r = 0; r < 4; r++) {
                int mm = mbase + i * 16 + quad * 4 + r;
                int nn = nbase + j * 16 + l16;
                att1[(size_t)mm * ATT + nn] = f2bf(acc[i][j][r] + be[nn]);
            }
}

// ---- once at end: preds = hall @ Wfc^T + bfc -> f32 out [b,t,v] (tiled MFMA) ----
__global__ __launch_bounds__(256) void k_predsall(const u16* __restrict__ hall,
                                                  const u16* __restrict__ Wfc,
                                                  const float* __restrict__ bfc,
                                                  float* __restrict__ out) {
    __shared__ u16 As[128 * 32];
    __shared__ u16 Bs[128 * 32];
    f32x4 acc[4][4];
    const f32x4 z = {0.f, 0.f, 0.f, 0.f};
    #pragma unroll
    for (int i = 0; i < 4; i++)
        #pragma unroll
        for (int j = 0; j < 4; j++) acc[i][j] = z;
    const u16* A  = hall + (size_t)blockIdx.x * 128 * DEC;
    const u16* Bm = Wfc  + (size_t)blockIdx.y * 128 * DEC;
    gemm128_body<DEC, DEC, 16>(A, Bm, As, Bs, acc);
    int tid = threadIdx.x, w = tid >> 6, lane = tid & 63;
    int wm = w >> 1, wn = w & 1, quad = lane >> 4, l16 = lane & 15;
    int mbase = blockIdx.x * 128 + wm * 64, nbase = blockIdx.y * 128 + wn * 64;
    #pragma unroll
    for (int i = 0; i < 4; i++)
        #pragma unroll
        for (int j = 0; j < 4; j++)
            #pragma unroll
            for (int r = 0; r < 4; r++) {
                int mm = mbase + i * 16 + quad * 4 + r;   // m = t*B + b
                int nn = nbase + j * 16 + l16;
                if (nn < V) {
                    int bb = mm & 31, tt = mm >> 5;
                    out[(size_t)bb * T * V + (size_t)tt * V + nn] = acc[i][j][r] + bfc[nn];
                }
            }
}

// ---- per step: fused e + softmax + awe + x-build. One block (512 thr) per b ----
__global__ __launch_bounds__(512) void k_attn(const u16* __restrict__ att1,
                                              const float* __restrict__ att2,
                                              const u16* __restrict__ enc_bf,
                                              const float* __restrict__ Wf,
                                              const float* __restrict__ bfa,
                                              const float* __restrict__ emb,
                                              const int* __restrict__ caps,
                                              float* __restrict__ out_alpha,
                                              u16* __restrict__ x, int t) {
    __shared__ float esh[256];
    __shared__ float sm[256];
    __shared__ float ash[P];
    int b = blockIdx.x, tid = threadIdx.x;
    int w = tid >> 6, lane = tid & 63;
    // per-lane invariant slices (k = lane*8 .. +8)
    float4 a20 = *reinterpret_cast<const float4*>(&att2[b * ATT + lane * 8]);
    float4 a21 = *reinterpret_cast<const float4*>(&att2[b * ATT + lane * 8 + 4]);
    float4 wf0 = *reinterpret_cast<const float4*>(&Wf[lane * 8]);
    float4 wf1 = *reinterpret_cast<const float4*>(&Wf[lane * 8 + 4]);
    float bias = bfa[0];
    // phase 1: e[p]
    for (int p = w; p < P; p += 8) {
        bf16x8 a1 = *reinterpret_cast<const bf16x8*>(&att1[((size_t)b * P + p) * ATT + lane * 8]);
        float v0 = fmaxf((float)a1[0] + a20.x, 0.f) * wf0.x;
        v0 += fmaxf((float)a1[1] + a20.y, 0.f) * wf0.y;
        v0 += fmaxf((float)a1[2] + a20.z, 0.f) * wf0.z;
        v0 += fmaxf((float)a1[3] + a20.w, 0.f) * wf0.w;
        v0 += fmaxf((float)a1[4] + a21.x, 0.f) * wf1.x;
        v0 += fmaxf((float)a1[5] + a21.y, 0.f) * wf1.y;
        v0 += fmaxf((float)a1[6] + a21.z, 0.f) * wf1.z;
        v0 += fmaxf((float)a1[7] + a21.w, 0.f) * wf1.w;
        v0 = wave_sum(v0);
        if (lane == 0) esh[p] = v0 + bias;
    }
    __syncthreads();
    // phase 2: softmax over P (first 256 threads)
    float v = -1e30f, ev = 0.f;
    if (tid < 256) { v = (tid < P) ? esh[tid] : -1e30f; sm[tid] = v; }
    __syncthreads();
    for (int s = 128; s > 0; s >>= 1) { if (tid < s) sm[tid] = fmaxf(sm[tid], sm[tid + s]); __syncthreads(); }
    float mx = sm[0];
    __syncthreads();
    if (tid < 256) { ev = (tid < P) ? expf(v - mx) : 0.f; sm[tid] = ev; }
    __syncthreads();
    for (int s = 128; s > 0; s >>= 1) { if (tid < s) sm[tid] += sm[tid + s]; __syncthreads(); }
    float inv = 1.0f / sm[0];
    if (tid < P) {
        float a = ev * inv;
        ash[tid] = a;
        out_alpha[(size_t)b * T * P + (size_t)t * P + tid] = a;
    }
    __syncthreads();
    // phase 3: awe (2048 cols, 4 per thread) + x build
    #pragma unroll
    for (int i = 0; i < 4; i++) {
        int ec = i * 512 + tid;
        const u16* ep = enc_bf + (size_t)b * P * ENC + ec;
        float acc = 0.f;
        for (int p = 0; p < P; p += 4) {
            acc += ash[p]     * bf2f(ep[(size_t)p * ENC]);
            acc += ash[p + 1] * bf2f(ep[(size_t)(p + 1) * ENC]);
            acc += ash[p + 2] * bf2f(ep[(size_t)(p + 2) * ENC]);
            acc += ash[p + 3] * bf2f(ep[(size_t)(p + 3) * ENC]);
        }
        x[b * KX + E + ec] = f2bf(acc);
    }
    if (tid < E) {
        int cap = caps[b * L + t];
        x[b * KX + tid] = f2bf(emb[(size_t)cap * E + tid]);
    }
}

// ---- per step: gates split-K x8 -> partials (MFMA, wave per 16x16 tile) ----
#define NSPLIT 8
#define KCH    352   // 2816/8, 11 MFMA steps
__global__ void k_gates(const u16* __restrict__ x, const u16* __restrict__ h,
                        const u16* __restrict__ Wih, const u16* __restrict__ Whh,
                        float* __restrict__ gpart) {
    int wid  = (blockIdx.x * 256 + threadIdx.x) >> 6;   // 2048 waves
    int lane = threadIdx.x & 63;
    int nt = wid & 127, mt = (wid >> 7) & 1, j = wid >> 8;
    int quad = lane >> 4, l16 = lane & 15;
    int m = mt * 16 + l16, n = nt * 16 + l16;
    f32x4 acc = {0.f, 0.f, 0.f, 0.f};
    for (int s = 0; s < 11; s++) {
        int k = j * KCH + s * 32 + quad * 8;
        bf16x8 a, bb;
        if (k < KX) {
            a  = *reinterpret_cast<const bf16x8*>(x   + m * KX + k);
            bb = *reinterpret_cast<const bf16x8*>(Wih + (size_t)n * KX + k);
        } else {
            int kh = k - KX;
            a  = *reinterpret_cast<const bf16x8*>(h   + m * DEC + kh);
            bb = *reinterpret_cast<const bf16x8*>(Whh + (size_t)n * DEC + kh);
        }
        acc = __builtin_amdgcn_mfma_f32_16x16x32_bf16(a, bb, acc, 0, 0, 0);
    }
    #pragma unroll
    for (int r = 0; r < 4; r++) {
        int mm = mt * 16 + quad * 4 + r, nn = nt * 16 + l16;
        gpart[((size_t)j * B + mm) * (4 * DEC) + nn] = acc[r];
    }
}

// ---- per step: sum partials + LSTM cell + att2 for next step. Block per b ----
__global__ __launch_bounds__(512) void k_cellatt2(const float* __restrict__ gpart,
                                                  const float* __restrict__ bih,
                                                  const float* __restrict__ bhh,
                                                  float* __restrict__ c,
                                                  u16* __restrict__ hbuf,
                                                  u16* __restrict__ hall,
                                                  const float* __restrict__ Wd,
                                                  const float* __restrict__ bd,
                                                  float* __restrict__ att2, int t) {
    __shared__ float hsh[DEC];
    int b = blockIdx.x, d = threadIdx.x;
    float g0 = bih[d] + bhh[d];
    float g1 = bih[DEC + d] + bhh[DEC + d];
    float g2 = bih[2 * DEC + d] + bhh[2 * DEC + d];
    float g3 = bih[3 * DEC + d] + bhh[3 * DEC + d];
    #pragma unroll
    for (int j = 0; j < NSPLIT; j++) {
        const float* gp = gpart + ((size_t)j * B + b) * (4 * DEC);
        g0 += gp[d]; g1 += gp[DEC + d]; g2 += gp[2 * DEC + d]; g3 += gp[3 * DEC + d];
    }
    float cn = sigf(g1) * c[b * DEC + d] + sigf(g0) * tanhf(g2);
    float hn = sigf(g3) * tanhf(cn);
    c[b * DEC + d] = cn;
    u16 hb = f2bf(hn);
    hbuf[b * DEC + d] = hb;
    hall[(size_t)(t * B + b) * DEC + d] = hb;
    hsh[d] = hn;
    __syncthreads();
    // att2[b, d] = h . Wd[d] + bd[d]
    const float4* wr = reinterpret_cast<const float4*>(Wd + (size_t)d * DEC);
    float acc = 0.f;
    for (int k4 = 0; k4 < DEC / 4; k4++) {
        float4 wv = wr[k4];
        acc += hsh[4 * k4] * wv.x + hsh[4 * k4 + 1] * wv.y
             + hsh[4 * k4 + 2] * wv.z + hsh[4 * k4 + 3] * wv.w;
    }
    att2[b * ATT + d] = acc + bd[d];
}

extern "C" void kernel_launch(void* const* d_in, const int* in_sizes, int n_in,
                              void* d_out, int out_size, void* d_ws, size_t ws_size,
                              hipStream_t stream) {
    const float* enc  = (const float*)d_in[0];
    const int*   caps = (const int*)d_in[1];
    const float* emb  = (const float*)d_in[3];
    const float* We   = (const float*)d_in[4];
    const float* be   = (const float*)d_in[5];
    const float* Wd   = (const float*)d_in[6];
    const float* bd   = (const float*)d_in[7];
    const float* Wf   = (const float*)d_in[8];
    const float* bfa  = (const float*)d_in[9];
    const float* Wih  = (const float*)d_in[10];
    const float* bih  = (const float*)d_in[11];
    const float* Whh  = (const float*)d_in[12];
    const float* bhh  = (const float*)d_in[13];
    const float* Wfc  = (const float*)d_in[14];
    const float* bfc  = (const float*)d_in[15];
    const float* Wh0  = (const float*)d_in[16];
    const float* bh0  = (const float*)d_in[17];
    const float* Wc0  = (const float*)d_in[18];
    const float* bc0  = (const float*)d_in[19];

    float* out_preds = (float*)d_out;
    float* out_alpha = (float*)d_out + (size_t)B * T * V;

    char* w = (char*)d_ws;
    size_t off = 0;
    auto carve = [&](size_t bytes) -> void* {
        void* p = w + off;
        off = (off + bytes + 255) & ~(size_t)255;
        return p;
    };
    u16*   enc_bf  = (u16*)  carve((size_t)B * P * ENC * 2);
    u16*   We_bf   = (u16*)  carve((size_t)ATT * ENC * 2);
    u16*   Wih_bf  = (u16*)  carve((size_t)4 * DEC * KX * 2);
    u16*   Whh_bf  = (u16*)  carve((size_t)4 * DEC * DEC * 2);
    u16*   Wfc_bf  = (u16*)  carve((size_t)VP * DEC * 2);
    u16*   att1_bf = (u16*)  carve((size_t)B * P * ATT * 2);
    float* meanb   = (float*)carve((size_t)B * ENC * 4);
    float* att2    = (float*)carve((size_t)B * ATT * 4);
    u16*   xbuf    = (u16*)  carve((size_t)B * KX * 2);
    u16*   hbuf    = (u16*)  carve((size_t)B * DEC * 2);
    float* cbuf    = (float*)carve((size_t)B * DEC * 4);
    float* gpart   = (float*)carve((size_t)NSPLIT * B * 4 * DEC * 4);
    u16*   hall    = (u16*)  carve((size_t)T * B * DEC * 2);
    (void)ws_size; (void)n_in; (void)in_sizes; (void)out_size;

    // one-time conversions
    k_f2b4 <<<(B * P * ENC) / 1024, 256, 0, stream>>>(enc, enc_bf, (B * P * ENC) / 4);
    k_f2b4 <<<(ATT * ENC) / 1024, 256, 0, stream>>>(We, We_bf, (ATT * ENC) / 4);
    k_f2b4 <<<(4 * DEC * KX) / 1024, 256, 0, stream>>>(Wih, Wih_bf, (4 * DEC * KX) / 4);
    k_f2b4 <<<(4 * DEC * DEC) / 1024, 256, 0, stream>>>(Whh, Whh_bf, (4 * DEC * DEC) / 4);
    k_f2bpad<<<(VP * DEC) / 1024, 256, 0, stream>>>(Wfc, Wfc_bf, V * DEC / 4, VP * DEC / 4);

    // init
    k_mean <<<(B * ENC) / 256, 256, 0, stream>>>(enc, meanb);
    k_h0c0 <<<(B * 2 * DEC * 64) / 256, 256, 0, stream>>>(meanb, Wh0, bh0, Wc0, bc0, hbuf, cbuf);
    k_att2w<<<(B * ATT * 64) / 256, 256, 0, stream>>>(hbuf, Wd, bd, att2);
    {
        dim3 g(B * P / 128, ATT / 128);   // 49 x 4
        k_att1t<<<g, 256, 0, stream>>>(enc_bf, We_bf, be, att1_bf);
    }

    // 20 sequential decode steps (3 kernels each)
    for (int t = 0; t < T; t++) {
        k_attn    <<<B, 512, 0, stream>>>(att1_bf, att2, enc_bf, Wf, bfa, emb, caps, out_alpha, xbuf, t);
        k_gates   <<<(2 * 128 * NSPLIT) / 4, 256, 0, stream>>>(xbuf, hbuf, Wih_bf, Whh_bf, gpart);
        k_cellatt2<<<B, 512, 0, stream>>>(gpart, bih, bhh, cbuf, hbuf, hall, Wd, bd, att2, t);
    }

    // one batched vocab projection for all 20 steps
    {
        dim3 g(T * B / 128, VP / 128);    // 5 x 235
        k_predsall<<<g, 256, 0, stream>>>(hall, Wfc_bf, bfc, out_preds);
    }
}